// Round 6
// baseline (653.211 us; speedup 1.0000x reference)
//
#include <hip/hip_runtime.h>
#include <math.h>

#define T_DIM 2048
#define S_DIM 2048
#define D_DIM 64
#define BH_DIM 32
#define U_SEL 614
#define QROWS 80
#define LOG_S_D 7.624618986159398
#define LOG2E_F 1.4426950408889634f
#define LN2_D 0.6931471805599453
#define SCL_Q (0.125f * LOG2E_F)  // q scale folded with log2e: scores in log2 domain

typedef __attribute__((ext_vector_type(8))) short bf16x8;
typedef __attribute__((ext_vector_type(4))) short bf16x4;
typedef __attribute__((ext_vector_type(4))) float f32x4;

__device__ __forceinline__ unsigned short bf16_rne(float x) {
  unsigned u = __float_as_uint(x);
  u += 0x7FFF + ((u >> 16) & 1);
  return (unsigned short)(u >> 16);
}
__device__ __forceinline__ float bf16_to_f(unsigned short h) {
  return __uint_as_float(((unsigned)h) << 16);
}
__device__ __forceinline__ float exp2_hw(float x) {
#if __has_builtin(__builtin_amdgcn_exp2f)
  return __builtin_amdgcn_exp2f(x);
#else
  float r;
  asm("v_exp_f32 %0, %1" : "=v"(r) : "v"(x));
  return r;
#endif
}

#define GLD_LDS16(g, l)                                                        \
  __builtin_amdgcn_global_load_lds(                                            \
      (const __attribute__((address_space(1))) unsigned int*)(const void*)(g), \
      (__attribute__((address_space(3))) unsigned int*)(void*)(l), 16, 0, 0)

// stage 16 KB image: 4 waves x 4 instr x 64 lanes x 16 B
__device__ __forceinline__ void stage_img16(const unsigned short* __restrict__ g,
                                            unsigned short* l, int lane, int w) {
#pragma unroll
  for (int it = 0; it < 4; ++it) {
    const int chunk = it * 4 + w;
    GLD_LDS16((const char*)g + chunk * 1024 + lane * 16, (char*)l + chunk * 1024);
  }
}
// stage 8 KB image: 4 waves x 2 instr
__device__ __forceinline__ void stage_img8(const unsigned short* __restrict__ g,
                                           unsigned short* l, int lane, int w) {
#pragma unroll
  for (int it = 0; it < 2; ++it) {
    const int chunk = it * 4 + w;
    GLD_LDS16((const char*)g + chunk * 1024 + lane * 16, (char*)l + chunk * 1024);
  }
}

// swizzled image, 64-wide rows: element (r,d) at r*64 + ((d>>3)^(r&7))*8 + (d&7)
__device__ __forceinline__ bf16x8 ldfrag_sw(const unsigned short* buf, int row, int chunk) {
  return *(const bf16x8*)(buf + (row << 6) + (((chunk) ^ (row & 7)) << 3));
}
// two stacked 64-row images (rows 0..127)
__device__ __forceinline__ bf16x8 ldfrag_k128(const unsigned short* buf, int row, int chunk) {
  return *(const bf16x8*)(buf + ((row >> 6) << 12) + ((row & 63) << 6) +
                          (((chunk) ^ (row & 7)) << 3));
}

// ====== convert: K,Q -> 64-row tiles [hi 8KB | lo 8KB] swizzled; V -> V^T; zero(out) ======
// Q images carry the 0.125*log2e scale folded in (Phase A stages them directly).
__global__ __launch_bounds__(256) void convert_kernel(
    const float* __restrict__ kin, const float* __restrict__ vin,
    const float* __restrict__ qin, unsigned short* __restrict__ kimg,
    unsigned short* __restrict__ vt_g, unsigned short* __restrict__ qimg,
    float* __restrict__ out) {
  __shared__ float vld[128][65];
  const int jb = blockIdx.x;
  const int tid = threadIdx.x;
  if (jb < 2048) {  // K (jb<1024) or Q (1024..2047): 32 bh x 32 tiles of 64 rows
    const bool isq = jb >= 1024;
    const int jj = jb & 1023;
    const int bh = jj >> 5, tl = jj & 31;
    const float* src = (isq ? qin : kin) + ((size_t)bh * 2048 + tl * 64) * 64;
    unsigned short* dst = (isq ? qimg : kimg) + (size_t)(bh * 32 + tl) * 8192;
    const float scl = isq ? SCL_Q : 1.0f;
#pragma unroll
    for (int g = 0; g < 2; ++g) {
      const int flat = g * 256 + tid;  // 512 chunks = 64 rows x 8
      const int r = flat >> 3, c = flat & 7;
      const float4 f0 = *(const float4*)(src + r * 64 + c * 8);
      const float4 f1 = *(const float4*)(src + r * 64 + c * 8 + 4);
      const float xs[8] = {f0.x, f0.y, f0.z, f0.w, f1.x, f1.y, f1.z, f1.w};
      bf16x8 hv, lv;
#pragma unroll
      for (int j = 0; j < 8; ++j) {
        const float x = xs[j] * scl;
        const unsigned short h = bf16_rne(x);
        hv[j] = (short)h;
        lv[j] = (short)bf16_rne(x - bf16_to_f(h));
      }
      const int base = (r << 6) + ((c ^ (r & 7)) << 3);
      *(bf16x8*)(dst + base) = hv;
      *(bf16x8*)(dst + 4096 + base) = lv;
    }
  } else if (jb < 2560) {  // V^T: [64 d][128 s] bf16, chunk ^ (d&15)
    const int jv = jb - 2048;
    const int bh = jv >> 4, tl = jv & 15;
    const float* src = vin + ((size_t)bh * 2048 + tl * 128) * 64;
#pragma unroll
    for (int g = 0; g < 8; ++g) {
      const int f = g * 256 + tid;
      const int r = f >> 4, c4 = f & 15;
      const float4 x = *(const float4*)(src + r * 64 + c4 * 4);
      vld[r][c4 * 4 + 0] = x.x;
      vld[r][c4 * 4 + 1] = x.y;
      vld[r][c4 * 4 + 2] = x.z;
      vld[r][c4 * 4 + 3] = x.w;
    }
    __syncthreads();
    unsigned short* dst = vt_g + (size_t)(bh * 16 + tl) * 8192;
#pragma unroll
    for (int g = 0; g < 4; ++g) {
      const int oc = g * 256 + tid;
      const int d = oc >> 4, cc = oc & 15;
      bf16x8 hv;
#pragma unroll
      for (int j = 0; j < 8; ++j) hv[j] = (short)bf16_rne(vld[cc * 8 + j][d]);
      *(bf16x8*)(dst + (d << 7) + (((cc ^ (d & 15))) << 3)) = hv;
    }
  } else {  // zero d_out: 512 blocks x 2048 float4
    float4* o4 = (float4*)out;
    const size_t b = (size_t)(jb - 2560);
#pragma unroll
    for (int g = 0; g < 8; ++g)
      o4[b * 2048 + g * 256 + tid] = make_float4(0.f, 0.f, 0.f, 0.f);
  }
}

// ====== Phase A: partial (Z,W) per (t-row, s-quarter), bf16x3 MFMA, BK=64 dbuf ======
// grid 2048: bh = b&31 (XCD-local), ttile = (b>>5)&15, squarter = b>>9.
// q staged from precomputed qimg (no per-block fp32->bf16x3 VALU); LDS 32 KB ->
// 5 blocks/CU resident (was ~2.4) to overlap VALU epilogue with other blocks' MFMA.
__global__ __launch_bounds__(256, 4) void kl_score_mfma(
    const unsigned short* __restrict__ qimg, const unsigned short* __restrict__ kimg,
    float2* __restrict__ zw) {
  __shared__ __align__(16) unsigned short lbuf[2][8192];  // 2 x 16 KB
  const int b = blockIdx.x;
  const int bh = b & 31;
  const int tt = (b >> 5) & 15;
  const int sq = b >> 9;
  const int tid = threadIdx.x;
  const int lane = tid & 63, w = tid >> 6, quad = lane >> 4, l15 = lane & 15;
  const unsigned short* qb = qimg + (size_t)(bh * 32 + tt * 2) * 8192;
  const unsigned short* kb = kimg + (size_t)bh * (32 * 8192);
  const int tg0 = sq * 8;

  // stage the 2 q tiles (rows 0-63, 64-127) into the K double-buffer
  stage_img16(qb, &lbuf[0][0], lane, w);
  stage_img16(qb + 8192, &lbuf[1][0], lane, w);
  __syncthreads();

  const unsigned short* lb = &lbuf[0][0];
  bf16x8 ah[2][2], al[2][2];  // persistent q A-fragments (wave w: t-rows w*32..w*32+31)
#pragma unroll
  for (int rt = 0; rt < 2; ++rt) {
    const int row = w * 32 + rt * 16 + l15;
    const int tile = row >> 6, r64 = row & 63;
#pragma unroll
    for (int kc = 0; kc < 2; ++kc) {
      const int off = tile * 8192 + (r64 << 6) + (((kc * 4 + quad) ^ (r64 & 7)) << 3);
      ah[rt][kc] = *(const bf16x8*)(lb + off);
      al[rt][kc] = *(const bf16x8*)(lb + 4096 + off);
    }
  }
  __syncthreads();  // all q frags in registers; lbuf free

  stage_img16(kb + (size_t)tg0 * 8192, &lbuf[0][0], lane, w);
  __syncthreads();  // drain tile 0

  float Zf[8], Wf[8];
#pragma unroll
  for (int i = 0; i < 8; ++i) { Zf[i] = 0.f; Wf[i] = 0.f; }

  for (int t = 0; t < 8; ++t) {
    if (t < 7)
      stage_img16(kb + (size_t)(tg0 + t + 1) * 8192, &lbuf[(t + 1) & 1][0], lane, w);
    const unsigned short* cb = &lbuf[t & 1][0];  // [hi 4096 | lo 4096] elems, 64 rows

    f32x4 acc[2][4];
#pragma unroll
    for (int rt = 0; rt < 2; ++rt)
#pragma unroll
      for (int ct = 0; ct < 4; ++ct) acc[rt][ct] = (f32x4){0.f, 0.f, 0.f, 0.f};

#pragma unroll
    for (int ct = 0; ct < 4; ++ct) {
      const int srow = ct * 16 + l15;
      const bf16x8 bh0 = ldfrag_sw(cb, srow, quad);
      const bf16x8 bl0 = ldfrag_sw(cb + 4096, srow, quad);
      const bf16x8 bh1 = ldfrag_sw(cb, srow, 4 + quad);
      const bf16x8 bl1 = ldfrag_sw(cb + 4096, srow, 4 + quad);
#pragma unroll
      for (int rt = 0; rt < 2; ++rt) {
        f32x4 c = acc[rt][ct];
        c = __builtin_amdgcn_mfma_f32_16x16x32_bf16(ah[rt][0], bh0, c, 0, 0, 0);
        c = __builtin_amdgcn_mfma_f32_16x16x32_bf16(al[rt][0], bh0, c, 0, 0, 0);
        c = __builtin_amdgcn_mfma_f32_16x16x32_bf16(ah[rt][0], bl0, c, 0, 0, 0);
        c = __builtin_amdgcn_mfma_f32_16x16x32_bf16(ah[rt][1], bh1, c, 0, 0, 0);
        c = __builtin_amdgcn_mfma_f32_16x16x32_bf16(al[rt][1], bh1, c, 0, 0, 0);
        c = __builtin_amdgcn_mfma_f32_16x16x32_bf16(ah[rt][1], bl1, c, 0, 0, 0);
        acc[rt][ct] = c;
      }
    }

    // no-max epilogue (log2 domain): e = 2^t, W += e*t  (fp32 accumulators)
#pragma unroll
    for (int rt = 0; rt < 2; ++rt)
#pragma unroll
      for (int r = 0; r < 4; ++r) {
        float zp = 0.f, wp = 0.f;
#pragma unroll
        for (int ct = 0; ct < 4; ++ct) {
          const float tv = acc[rt][ct][r];
          const float e = exp2_hw(tv);
          zp += e;
          wp = fmaf(e, tv, wp);
        }
        Zf[rt * 4 + r] += zp;
        Wf[rt * 4 + r] += wp;
      }
    __syncthreads();  // readers done; drains prefetch of t+1
  }

#pragma unroll
  for (int i = 0; i < 8; ++i) {
    float Zt = Zf[i], Wt = Wf[i];
#pragma unroll
    for (int mask = 1; mask <= 8; mask <<= 1) {
      Zt += __shfl_xor(Zt, mask);
      Wt += __shfl_xor(Wt, mask);
    }
    if (l15 == 0) {
      const int row = tt * 128 + w * 32 + (i >> 2) * 16 + quad * 4 + (i & 3);
      zw[((size_t)sq * 32 + bh) * 2048 + row] = make_float2(Zt, Wt);
    }
  }
}

// ====== Phase B: kl from (Z,W) quarters + exact top-614, bitonic, 1024 threads ======
__global__ __launch_bounds__(1024) void topk_kernel(const float2* __restrict__ zw,
                                                    int* __restrict__ topk) {
  __shared__ float sv[2048];
  __shared__ int si[2048];
  const int bh = blockIdx.x;
  const int tid = threadIdx.x;
  for (int i = tid; i < 2048; i += 1024) {
    double Z = 0.0, W = 0.0;
#pragma unroll
    for (int sq = 0; sq < 4; ++sq) {
      const float2 a = zw[((size_t)sq * 32 + bh) * 2048 + i];
      Z += (double)a.x;
      W += (double)a.y;
    }
    sv[i] = (float)(LN2_D * (W / Z) - log(Z) + LOG_S_D);
    si[i] = i;
  }
  __syncthreads();
  for (int kk = 2; kk <= 2048; kk <<= 1) {
    for (int j = kk >> 1; j > 0; j >>= 1) {
      const int p = tid;
      const int i = ((p & ~(j - 1)) << 1) | (p & (j - 1));
      const int pr = i | j;
      const float v1 = sv[i], v2 = sv[pr];
      const int i1 = si[i], i2 = si[pr];
      const bool beforePI = (v2 > v1) || (v2 == v1 && i2 < i1);
      const bool dirDesc = ((i & kk) == 0);
      const bool doSwap = dirDesc ? beforePI : !beforePI;
      if (doSwap) { sv[i] = v2; sv[pr] = v1; si[i] = i2; si[pr] = i1; }
      __syncthreads();
    }
  }
  for (int i = tid; i < U_SEL; i += 1024) topk[bh * U_SEL + i] = si[i];
}

// ====== Phase C: bf16 MFMA attention, 256 blocks = EXACTLY 1 block/CU ======
// Round-4/5 lesson: wall time = per-block serial time x worst-CU block count.
// Perfectly balanced grid (8 l-tiles x 80 rows x 32 bh = 256 blocks), full
// 2048-s loop per block, ps-LDS P path, K+V double-buffered, one barrier/iter.
struct __align__(16) SmC {
  union { unsigned short kt[2][8192]; float obuf[QROWS * 64]; } a;  // 32 KB (obuf after loop)
  union { unsigned short vt[2][8192]; float zred[4][QROWS]; } b;    // 32 KB (zred after loop)
  unsigned short qs[QROWS * 64];                                    // 10 KB
  unsigned short ps[4][QROWS * 40];                                 // 25.6 KB
};

// grid 256: bh = b&31 (XCD-affine), lt = b>>5
__global__ __launch_bounds__(256, 1) void sparse_attn_mfma(
    const float* __restrict__ q, const unsigned short* __restrict__ kimg,
    const unsigned short* __restrict__ vt_g, const int* __restrict__ topk,
    float* __restrict__ out) {
  __shared__ SmC sm;
  const int b = blockIdx.x;
  const int bh = b & 31;
  const int l0 = (b >> 5) * QROWS;
  const int tid = threadIdx.x;
  const int lane = tid & 63, w = tid >> 6, quad = lane >> 4, l15 = lane & 15;
  const float* qb = q + (size_t)bh * (2048 * 64);
  const unsigned short* kb = kimg + (size_t)bh * (32 * 8192);
  const unsigned short* vtb = vt_g + (size_t)bh * (16 * 8192);
  const int* tkb = topk + bh * U_SEL;

  {  // gather 80 selected q rows -> bf16 * (0.125*log2e), swizzled image in LDS
#pragma unroll
    for (int g = 0; g < 3; ++g) {
      const int ch = g * 256 + tid;
      if (ch < QROWS * 8) {
        const int r = ch >> 3, c = ch & 7;
        const int l = l0 + r;
        const int row = (l < U_SEL) ? tkb[l] : tkb[0];
        const float4 f0 = *(const float4*)(qb + (size_t)row * 64 + c * 8);
        const float4 f1 = *(const float4*)(qb + (size_t)row * 64 + c * 8 + 4);
        const float xs[8] = {f0.x, f0.y, f0.z, f0.w, f1.x, f1.y, f1.z, f1.w};
        bf16x8 hv;
#pragma unroll
        for (int j = 0; j < 8; ++j) hv[j] = (short)bf16_rne(xs[j] * SCL_Q);
        *(bf16x8*)&sm.qs[(r << 6) + ((c ^ (r & 7)) << 3)] = hv;
      }
    }
  }
  // prologue: stage tile 0 (K-hi 16 KB + V^T 16 KB) into buffer 0
  stage_img8(kb, sm.a.kt[0], lane, w);
  stage_img8(kb + 8192, sm.a.kt[0] + 4096, lane, w);
  stage_img16(vtb, sm.b.vt[0], lane, w);
  __syncthreads();  // qs ready + tile 0 drained

  bf16x8 qf[5][2];  // persistent q B-fragments (80 rows -> 5 nt tiles)
#pragma unroll
  for (int nt = 0; nt < 5; ++nt)
#pragma unroll
    for (int kc = 0; kc < 2; ++kc)
      qf[nt][kc] = ldfrag_sw(sm.qs, nt * 16 + l15, kc * 4 + quad);

  float zrun[5] = {0.f, 0.f, 0.f, 0.f, 0.f};
  f32x4 oacc[5][4];
#pragma unroll
  for (int a = 0; a < 5; ++a)
#pragma unroll
    for (int b2 = 0; b2 < 4; ++b2) oacc[a][b2] = (f32x4){0.f, 0.f, 0.f, 0.f};

  for (int st = 0; st < 16; ++st) {
    // prefetch tile st+1 into the other buffer; drained by the single barrier.
    if (st < 15) {
      unsigned short* kd = sm.a.kt[(st + 1) & 1];
      unsigned short* vd = sm.b.vt[(st + 1) & 1];
      stage_img8(kb + (size_t)(2 * st + 2) * 8192, kd, lane, w);
      stage_img8(kb + (size_t)(2 * st + 3) * 8192, kd + 4096, lane, w);
      stage_img16(vtb + (size_t)(st + 1) * 8192, vd, lane, w);
    }
    const unsigned short* kcur = sm.a.kt[st & 1];
    const unsigned short* vcur = sm.b.vt[st & 1];

    // S^T = K·q^T : C[m=s][n=qr]; wave w owns s in [w*32, w*32+32)
    const int ar0 = w * 32 + l15, ar1 = w * 32 + 16 + l15;
    const bf16x8 a00 = ldfrag_k128(kcur, ar0, quad);
    const bf16x8 a01 = ldfrag_k128(kcur, ar0, 4 + quad);
    const bf16x8 a10 = ldfrag_k128(kcur, ar1, quad);
    const bf16x8 a11 = ldfrag_k128(kcur, ar1, 4 + quad);

    f32x4 sacc[2][5];
    __builtin_amdgcn_s_setprio(1);
#pragma unroll
    for (int mt = 0; mt < 2; ++mt)
#pragma unroll
      for (int nt = 0; nt < 5; ++nt) {
        f32x4 c = (f32x4){0.f, 0.f, 0.f, 0.f};
        c = __builtin_amdgcn_mfma_f32_16x16x32_bf16(mt ? a10 : a00, qf[nt][0], c, 0, 0, 0);
        c = __builtin_amdgcn_mfma_f32_16x16x32_bf16(mt ? a11 : a01, qf[nt][1], c, 0, 0, 0);
        sacc[mt][nt] = c;
      }
    __builtin_amdgcn_s_setprio(0);

    // no-max: p = 2^t; wave-local ps round-trip (no barrier needed)
#pragma unroll
    for (int nt = 0; nt < 5; ++nt) {
      float zl = 0.f;
#pragma unroll
      for (int mt = 0; mt < 2; ++mt) {
        bf16x4 pw;
#pragma unroll
        for (int r = 0; r < 4; ++r) {
          const float p = exp2_hw(sacc[mt][nt][r]);
          zl += p;
          pw[r] = (short)bf16_rne(p);
        }
        *(bf16x4*)&sm.ps[w][(nt * 16 + l15) * 40 + mt * 16 + quad * 4] = pw;
      }
      zrun[nt] += zl;
    }

    // V fragments from LDS
    bf16x8 vbf[4];
#pragma unroll
    for (int dt = 0; dt < 4; ++dt) {
      const int d = dt * 16 + l15;
      vbf[dt] = *(const bf16x8*)&vcur[(d << 7) + (((w * 4 + quad) ^ l15) << 3)];
    }

    // PV: O[qr][d] += P[qr][s]·V[s][d]
    __builtin_amdgcn_s_setprio(1);
#pragma unroll
    for (int mtq = 0; mtq < 5; ++mtq) {
      const bf16x8 pa = *(const bf16x8*)&sm.ps[w][(mtq * 16 + l15) * 40 + quad * 8];
#pragma unroll
      for (int dt = 0; dt < 4; ++dt)
        oacc[mtq][dt] = __builtin_amdgcn_mfma_f32_16x16x32_bf16(pa, vbf[dt], oacc[mtq][dt], 0, 0, 0);
    }
    __builtin_amdgcn_s_setprio(0);
    __syncthreads();  // readers of buf[st&1] done + drains prefetch of st+1
  }

  // Z: reduce over quads in-wave, stash per-wave rows (zred unions dead vt)
#pragma unroll
  for (int nt = 0; nt < 5; ++nt) {
    float z = zrun[nt];
    z += __shfl_xor(z, 16);
    z += __shfl_xor(z, 32);
    if (quad == 0) sm.b.zred[w][nt * 16 + l15] = z;
  }
  for (int i = tid; i < QROWS * 64; i += 256) sm.a.obuf[i] = 0.f;
  __syncthreads();
#pragma unroll
  for (int mtq = 0; mtq < 5; ++mtq)
#pragma unroll
    for (int r = 0; r < 4; ++r) {
      const int qr = mtq * 16 + quad * 4 + r;
#pragma unroll
      for (int dt = 0; dt < 4; ++dt)
        atomicAdd(&sm.a.obuf[qr * 64 + dt * 16 + l15], oacc[mtq][dt][r]);
    }
  __syncthreads();
  {  // normalized direct store: 80 rows x 4 segs = 320 work items
#pragma unroll
    for (int it = 0; it < 2; ++it) {
      const int tt = it * 256 + tid;
      if (tt < QROWS * 4) {
        const int qr = tt >> 2, seg = tt & 3;
        const int l = l0 + qr;
        if (l < U_SEL) {
          const float Zt = sm.b.zred[0][qr] + sm.b.zred[1][qr] +
                           sm.b.zred[2][qr] + sm.b.zred[3][qr];
          const float inv = 1.0f / Zt;
          const int row = tkb[l];
          float* op = &out[((size_t)bh * T_DIM + row) * 64 + seg * 16];
          const float* ob = &sm.a.obuf[qr * 64 + seg * 16];
#pragma unroll
          for (int j = 0; j < 4; ++j) {
            float4 o;
            o.x = ob[j * 4 + 0] * inv;
            o.y = ob[j * 4 + 1] * inv;
            o.z = ob[j * 4 + 2] * inv;
            o.w = ob[j * 4 + 3] * inv;
            *(float4*)&op[j * 4] = o;
          }
        }
      }
    }
  }
}

extern "C" void kernel_launch(void* const* d_in, const int* in_sizes, int n_in,
                              void* d_out, int out_size, void* d_ws, size_t ws_size,
                              hipStream_t stream) {
  const float* q = (const float*)d_in[0];
  const float* k = (const float*)d_in[1];
  const float* v = (const float*)d_in[2];
  float* out = (float*)d_out;
  // workspace: zw 2MB | topk 80KB | kimg 16MB | vt 8MB | qimg 16MB (~42.1MB)
  char* ws = (char*)d_ws;
  float2* zw = (float2*)ws;                                  // [4][32][2048] float2
  int* topk = (int*)(ws + 2097152);
  unsigned short* kimg = (unsigned short*)(ws + 2179072);    // 32 bh x 32 tiles x 16 KB
  unsigned short* vt_g = (unsigned short*)(ws + 18956288);   // 32 bh x 16 tiles x 16 KB
  unsigned short* qimg = (unsigned short*)(ws + 27344896);   // 32 bh x 32 tiles x 16 KB

  convert_kernel<<<dim3(3072), dim3(256), 0, stream>>>(k, v, q, kimg, vt_g, qimg, out);
  kl_score_mfma<<<dim3(2048), dim3(256), 0, stream>>>(qimg, kimg, zw);
  topk_kernel<<<dim3(BH_DIM), dim3(1024), 0, stream>>>(zw, topk);
  sparse_attn_mfma<<<dim3(256), dim3(256), 0, stream>>>(q, kimg, vt_g, topk, out);
}

// Round 7
// 232.607 us; speedup vs baseline: 2.8082x; 2.8082x over previous
//
#include <hip/hip_runtime.h>
#include <math.h>

#define T_DIM 2048
#define S_DIM 2048
#define D_DIM 64
#define BH_DIM 32
#define U_SEL 614
#define QROWS 80
#define LOG_S_D 7.624618986159398
#define LOG2E_F 1.4426950408889634f
#define LN2_D 0.6931471805599453
#define SCL_Q (0.125f * LOG2E_F)  // q scale folded with log2e: scores in log2 domain

typedef __attribute__((ext_vector_type(8))) short bf16x8;
typedef __attribute__((ext_vector_type(4))) short bf16x4;
typedef __attribute__((ext_vector_type(4))) float f32x4;

__device__ __forceinline__ unsigned short bf16_rne(float x) {
  unsigned u = __float_as_uint(x);
  u += 0x7FFF + ((u >> 16) & 1);
  return (unsigned short)(u >> 16);
}
__device__ __forceinline__ float bf16_to_f(unsigned short h) {
  return __uint_as_float(((unsigned)h) << 16);
}

#define GLD_LDS16(g, l)                                                        \
  __builtin_amdgcn_global_load_lds(                                            \
      (const __attribute__((address_space(1))) unsigned int*)(const void*)(g), \
      (__attribute__((address_space(3))) unsigned int*)(void*)(l), 16, 0, 0)

// stage 16 KB image: 4 waves x 4 instr x 64 lanes x 16 B
__device__ __forceinline__ void stage_img16(const unsigned short* __restrict__ g,
                                            unsigned short* l, int lane, int w) {
#pragma unroll
  for (int it = 0; it < 4; ++it) {
    const int chunk = it * 4 + w;
    GLD_LDS16((const char*)g + chunk * 1024 + lane * 16, (char*)l + chunk * 1024);
  }
}
// stage 8 KB image: 4 waves x 2 instr
__device__ __forceinline__ void stage_img8(const unsigned short* __restrict__ g,
                                           unsigned short* l, int lane, int w) {
#pragma unroll
  for (int it = 0; it < 2; ++it) {
    const int chunk = it * 4 + w;
    GLD_LDS16((const char*)g + chunk * 1024 + lane * 16, (char*)l + chunk * 1024);
  }
}

// swizzled image, 64-wide rows: element (r,d) at r*64 + ((d>>3)^(r&7))*8 + (d&7)
__device__ __forceinline__ bf16x8 ldfrag_sw(const unsigned short* buf, int row, int chunk) {
  return *(const bf16x8*)(buf + (row << 6) + (((chunk) ^ (row & 7)) << 3));
}
// two stacked 64-row images (rows 0..127)
__device__ __forceinline__ bf16x8 ldfrag_k128(const unsigned short* buf, int row, int chunk) {
  return *(const bf16x8*)(buf + ((row >> 6) << 12) + ((row & 63) << 6) +
                          (((chunk) ^ (row & 7)) << 3));
}

// ====== convert: K,Q -> 64-row tiles [hi 8KB | lo 8KB] swizzled; V -> V^T; zero(out) ======
// Q images carry the 0.125*log2e scale folded in (Phase A stages them directly).
__global__ __launch_bounds__(256) void convert_kernel(
    const float* __restrict__ kin, const float* __restrict__ vin,
    const float* __restrict__ qin, unsigned short* __restrict__ kimg,
    unsigned short* __restrict__ vt_g, unsigned short* __restrict__ qimg,
    float* __restrict__ out) {
  __shared__ float vld[128][65];
  const int jb = blockIdx.x;
  const int tid = threadIdx.x;
  if (jb < 2048) {  // K (jb<1024) or Q (1024..2047): 32 bh x 32 tiles of 64 rows
    const bool isq = jb >= 1024;
    const int jj = jb & 1023;
    const int bh = jj >> 5, tl = jj & 31;
    const float* src = (isq ? qin : kin) + ((size_t)bh * 2048 + tl * 64) * 64;
    unsigned short* dst = (isq ? qimg : kimg) + (size_t)(bh * 32 + tl) * 8192;
    const float scl = isq ? SCL_Q : 1.0f;
#pragma unroll
    for (int g = 0; g < 2; ++g) {
      const int flat = g * 256 + tid;  // 512 chunks = 64 rows x 8
      const int r = flat >> 3, c = flat & 7;
      const float4 f0 = *(const float4*)(src + r * 64 + c * 8);
      const float4 f1 = *(const float4*)(src + r * 64 + c * 8 + 4);
      const float xs[8] = {f0.x, f0.y, f0.z, f0.w, f1.x, f1.y, f1.z, f1.w};
      bf16x8 hv, lv;
#pragma unroll
      for (int j = 0; j < 8; ++j) {
        const float x = xs[j] * scl;
        const unsigned short h = bf16_rne(x);
        hv[j] = (short)h;
        lv[j] = (short)bf16_rne(x - bf16_to_f(h));
      }
      const int base = (r << 6) + ((c ^ (r & 7)) << 3);
      *(bf16x8*)(dst + base) = hv;
      *(bf16x8*)(dst + 4096 + base) = lv;
    }
  } else if (jb < 2560) {  // V^T: [64 d][128 s] bf16, chunk ^ (d&15)
    const int jv = jb - 2048;
    const int bh = jv >> 4, tl = jv & 15;
    const float* src = vin + ((size_t)bh * 2048 + tl * 128) * 64;
#pragma unroll
    for (int g = 0; g < 8; ++g) {
      const int f = g * 256 + tid;
      const int r = f >> 4, c4 = f & 15;
      const float4 x = *(const float4*)(src + r * 64 + c4 * 4);
      vld[r][c4 * 4 + 0] = x.x;
      vld[r][c4 * 4 + 1] = x.y;
      vld[r][c4 * 4 + 2] = x.z;
      vld[r][c4 * 4 + 3] = x.w;
    }
    __syncthreads();
    unsigned short* dst = vt_g + (size_t)(bh * 16 + tl) * 8192;
#pragma unroll
    for (int g = 0; g < 4; ++g) {
      const int oc = g * 256 + tid;
      const int d = oc >> 4, cc = oc & 15;
      bf16x8 hv;
#pragma unroll
      for (int j = 0; j < 8; ++j) hv[j] = (short)bf16_rne(vld[cc * 8 + j][d]);
      *(bf16x8*)(dst + (d << 7) + (((cc ^ (d & 15))) << 3)) = hv;
    }
  } else {  // zero d_out: 512 blocks x 2048 float4
    float4* o4 = (float4*)out;
    const size_t b = (size_t)(jb - 2560);
#pragma unroll
    for (int g = 0; g < 8; ++g)
      o4[b * 2048 + g * 256 + tid] = make_float4(0.f, 0.f, 0.f, 0.f);
  }
}

// ====== Phase A: partial (Z,W) per (t-row, s-half), bf16x3 MFMA, BK=64 dbuf ======
// grid 1024: bh = b&31 (XCD-local), ttile = (b>>5)&15, shalf = b>>9.
// ROUND-6 LESSON: co-resident same-bh blocks MUST walk the same K stream in
// lockstep (shalf 2-way only); 4-way s-sharding destroyed L2 temporal sharing
// (FETCH 16MB -> 850MB, 7x slower). q staged from precomputed qimg (no per-block
// fp32->bf16x3 VALU); loop body identical to the proven round-5 kernel.
__global__ __launch_bounds__(256, 4) void kl_score_mfma(
    const unsigned short* __restrict__ qimg, const unsigned short* __restrict__ kimg,
    float2* __restrict__ zw) {
  __shared__ __align__(16) unsigned short lbuf[2][8192];  // 2 x 16 KB
  const int b = blockIdx.x;
  const int bh = b & 31;
  const int tt = (b >> 5) & 15;
  const int shalf = b >> 9;
  const int tid = threadIdx.x;
  const int lane = tid & 63, w = tid >> 6, quad = lane >> 4, l15 = lane & 15;
  const unsigned short* qb = qimg + (size_t)(bh * 32 + tt * 2) * 8192;
  const unsigned short* kb = kimg + (size_t)bh * (32 * 8192);
  const int tg0 = shalf * 16;

  // stage the 2 q tiles (rows 0-63 -> lbuf[0], rows 64-127 -> lbuf[1])
  stage_img16(qb, &lbuf[0][0], lane, w);
  stage_img16(qb + 8192, &lbuf[1][0], lane, w);
  __syncthreads();

  bf16x8 ah[2][2], al[2][2];  // persistent q A-fragments (wave w: t-rows w*32..w*32+31)
#pragma unroll
  for (int rt = 0; rt < 2; ++rt) {
    const int row = w * 32 + rt * 16 + l15;
    const unsigned short* lb = &lbuf[row >> 6][0];  // [hi 4096 | lo 4096] per tile
    const int r64 = row & 63;
#pragma unroll
    for (int kc = 0; kc < 2; ++kc) {
      const int off = (r64 << 6) + (((kc * 4 + quad) ^ (r64 & 7)) << 3);
      ah[rt][kc] = *(const bf16x8*)(lb + off);
      al[rt][kc] = *(const bf16x8*)(lb + 4096 + off);
    }
  }
  __syncthreads();  // all q frags in registers; lbuf free

  stage_img16(kb + (size_t)tg0 * 8192, &lbuf[0][0], lane, w);
  __syncthreads();  // drain tile 0

  float Zf[8], Wf[8];
#pragma unroll
  for (int i = 0; i < 8; ++i) { Zf[i] = 0.f; Wf[i] = 0.f; }

  for (int t = 0; t < 16; ++t) {
    if (t < 15)
      stage_img16(kb + (size_t)(tg0 + t + 1) * 8192, &lbuf[(t + 1) & 1][0], lane, w);
    const unsigned short* cb = &lbuf[t & 1][0];  // [hi 4096 | lo 4096] elems, 64 rows

    f32x4 acc[2][4];
#pragma unroll
    for (int rt = 0; rt < 2; ++rt)
#pragma unroll
      for (int ct = 0; ct < 4; ++ct) acc[rt][ct] = (f32x4){0.f, 0.f, 0.f, 0.f};

#pragma unroll
    for (int ct = 0; ct < 4; ++ct) {
      const int srow = ct * 16 + l15;
      const bf16x8 bh0 = ldfrag_sw(cb, srow, quad);
      const bf16x8 bl0 = ldfrag_sw(cb + 4096, srow, quad);
      const bf16x8 bh1 = ldfrag_sw(cb, srow, 4 + quad);
      const bf16x8 bl1 = ldfrag_sw(cb + 4096, srow, 4 + quad);
#pragma unroll
      for (int rt = 0; rt < 2; ++rt) {
        f32x4 c = acc[rt][ct];
        c = __builtin_amdgcn_mfma_f32_16x16x32_bf16(ah[rt][0], bh0, c, 0, 0, 0);
        c = __builtin_amdgcn_mfma_f32_16x16x32_bf16(al[rt][0], bh0, c, 0, 0, 0);
        c = __builtin_amdgcn_mfma_f32_16x16x32_bf16(ah[rt][0], bl0, c, 0, 0, 0);
        c = __builtin_amdgcn_mfma_f32_16x16x32_bf16(ah[rt][1], bh1, c, 0, 0, 0);
        c = __builtin_amdgcn_mfma_f32_16x16x32_bf16(al[rt][1], bh1, c, 0, 0, 0);
        c = __builtin_amdgcn_mfma_f32_16x16x32_bf16(ah[rt][1], bl1, c, 0, 0, 0);
        acc[rt][ct] = c;
      }
    }

    // no-max epilogue (log2 domain): e = 2^t, W += e*t  (fp32 accumulators)
#pragma unroll
    for (int rt = 0; rt < 2; ++rt)
#pragma unroll
      for (int r = 0; r < 4; ++r) {
        float zp = 0.f, wp = 0.f;
#pragma unroll
        for (int ct = 0; ct < 4; ++ct) {
          const float tv = acc[rt][ct][r];
          const float e = exp2f(tv);
          zp += e;
          wp = fmaf(e, tv, wp);
        }
        Zf[rt * 4 + r] += zp;
        Wf[rt * 4 + r] += wp;
      }
    __syncthreads();  // readers done; drains prefetch of t+1
  }

#pragma unroll
  for (int i = 0; i < 8; ++i) {
    float Zt = Zf[i], Wt = Wf[i];
#pragma unroll
    for (int mask = 1; mask <= 8; mask <<= 1) {
      Zt += __shfl_xor(Zt, mask);
      Wt += __shfl_xor(Wt, mask);
    }
    if (l15 == 0) {
      const int row = tt * 128 + w * 32 + (i >> 2) * 16 + quad * 4 + (i & 3);
      zw[((size_t)shalf * 32 + bh) * 2048 + row] = make_float2(Zt, Wt);
    }
  }
}

// ====== Phase B: kl from (Z,W) halves + exact top-614, bitonic, 1024 threads ======
__global__ __launch_bounds__(1024) void topk_kernel(const float2* __restrict__ zw,
                                                    int* __restrict__ topk) {
  __shared__ float sv[2048];
  __shared__ int si[2048];
  const int bh = blockIdx.x;
  const int tid = threadIdx.x;
  for (int i = tid; i < 2048; i += 1024) {
    const float2 a = zw[(size_t)bh * 2048 + i];
    const float2 c = zw[(size_t)(32 + bh) * 2048 + i];
    const double Z = (double)a.x + (double)c.x;
    const double W = (double)a.y + (double)c.y;
    sv[i] = (float)(LN2_D * (W / Z) - log(Z) + LOG_S_D);
    si[i] = i;
  }
  __syncthreads();
  for (int kk = 2; kk <= 2048; kk <<= 1) {
    for (int j = kk >> 1; j > 0; j >>= 1) {
      const int p = tid;
      const int i = ((p & ~(j - 1)) << 1) | (p & (j - 1));
      const int pr = i | j;
      const float v1 = sv[i], v2 = sv[pr];
      const int i1 = si[i], i2 = si[pr];
      const bool beforePI = (v2 > v1) || (v2 == v1 && i2 < i1);
      const bool dirDesc = ((i & kk) == 0);
      const bool doSwap = dirDesc ? beforePI : !beforePI;
      if (doSwap) { sv[i] = v2; sv[pr] = v1; si[i] = i2; si[pr] = i1; }
      __syncthreads();
    }
  }
  for (int i = tid; i < U_SEL; i += 1024) topk[bh * U_SEL + i] = si[i];
}

// ====== Phase C: bf16 MFMA attention, 256 blocks = EXACTLY 1 block/CU ======
// Round-4/5 lesson: wall time = per-block serial time x worst-CU block count.
// Perfectly balanced grid (8 l-tiles x 80 rows x 32 bh = 256 blocks), full
// 2048-s loop per block, ps-LDS P path, K+V double-buffered, one barrier/iter.
struct __align__(16) SmC {
  union { unsigned short kt[2][8192]; float obuf[QROWS * 64]; } a;  // 32 KB (obuf after loop)
  union { unsigned short vt[2][8192]; float zred[4][QROWS]; } b;    // 32 KB (zred after loop)
  unsigned short qs[QROWS * 64];                                    // 10 KB
  unsigned short ps[4][QROWS * 40];                                 // 25.6 KB
};

// grid 256: bh = b&31 (XCD-affine), lt = b>>5
__global__ __launch_bounds__(256, 1) void sparse_attn_mfma(
    const float* __restrict__ q, const unsigned short* __restrict__ kimg,
    const unsigned short* __restrict__ vt_g, const int* __restrict__ topk,
    float* __restrict__ out) {
  __shared__ SmC sm;
  const int b = blockIdx.x;
  const int bh = b & 31;
  const int l0 = (b >> 5) * QROWS;
  const int tid = threadIdx.x;
  const int lane = tid & 63, w = tid >> 6, quad = lane >> 4, l15 = lane & 15;
  const float* qb = q + (size_t)bh * (2048 * 64);
  const unsigned short* kb = kimg + (size_t)bh * (32 * 8192);
  const unsigned short* vtb = vt_g + (size_t)bh * (16 * 8192);
  const int* tkb = topk + bh * U_SEL;

  {  // gather 80 selected q rows -> bf16 * (0.125*log2e), swizzled image in LDS
#pragma unroll
    for (int g = 0; g < 3; ++g) {
      const int ch = g * 256 + tid;
      if (ch < QROWS * 8) {
        const int r = ch >> 3, c = ch & 7;
        const int l = l0 + r;
        const int row = (l < U_SEL) ? tkb[l] : tkb[0];
        const float4 f0 = *(const float4*)(qb + (size_t)row * 64 + c * 8);
        const float4 f1 = *(const float4*)(qb + (size_t)row * 64 + c * 8 + 4);
        const float xs[8] = {f0.x, f0.y, f0.z, f0.w, f1.x, f1.y, f1.z, f1.w};
        bf16x8 hv;
#pragma unroll
        for (int j = 0; j < 8; ++j) hv[j] = (short)bf16_rne(xs[j] * SCL_Q);
        *(bf16x8*)&sm.qs[(r << 6) + ((c ^ (r & 7)) << 3)] = hv;
      }
    }
  }
  // prologue: stage tile 0 (K-hi 16 KB + V^T 16 KB) into buffer 0
  stage_img8(kb, sm.a.kt[0], lane, w);
  stage_img8(kb + 8192, sm.a.kt[0] + 4096, lane, w);
  stage_img16(vtb, sm.b.vt[0], lane, w);
  __syncthreads();  // qs ready + tile 0 drained

  bf16x8 qf[5][2];  // persistent q B-fragments (80 rows -> 5 nt tiles)
#pragma unroll
  for (int nt = 0; nt < 5; ++nt)
#pragma unroll
    for (int kc = 0; kc < 2; ++kc)
      qf[nt][kc] = ldfrag_sw(sm.qs, nt * 16 + l15, kc * 4 + quad);

  float zrun[5] = {0.f, 0.f, 0.f, 0.f, 0.f};
  f32x4 oacc[5][4];
#pragma unroll
  for (int a = 0; a < 5; ++a)
#pragma unroll
    for (int b2 = 0; b2 < 4; ++b2) oacc[a][b2] = (f32x4){0.f, 0.f, 0.f, 0.f};

  for (int st = 0; st < 16; ++st) {
    // prefetch tile st+1 into the other buffer; drained by the single barrier.
    if (st < 15) {
      unsigned short* kd = sm.a.kt[(st + 1) & 1];
      unsigned short* vd = sm.b.vt[(st + 1) & 1];
      stage_img8(kb + (size_t)(2 * st + 2) * 8192, kd, lane, w);
      stage_img8(kb + (size_t)(2 * st + 3) * 8192, kd + 4096, lane, w);
      stage_img16(vtb + (size_t)(st + 1) * 8192, vd, lane, w);
    }
    const unsigned short* kcur = sm.a.kt[st & 1];
    const unsigned short* vcur = sm.b.vt[st & 1];

    // S^T = K·q^T : C[m=s][n=qr]; wave w owns s in [w*32, w*32+32)
    const int ar0 = w * 32 + l15, ar1 = w * 32 + 16 + l15;
    const bf16x8 a00 = ldfrag_k128(kcur, ar0, quad);
    const bf16x8 a01 = ldfrag_k128(kcur, ar0, 4 + quad);
    const bf16x8 a10 = ldfrag_k128(kcur, ar1, quad);
    const bf16x8 a11 = ldfrag_k128(kcur, ar1, 4 + quad);

    f32x4 sacc[2][5];
    __builtin_amdgcn_s_setprio(1);
#pragma unroll
    for (int mt = 0; mt < 2; ++mt)
#pragma unroll
      for (int nt = 0; nt < 5; ++nt) {
        f32x4 c = (f32x4){0.f, 0.f, 0.f, 0.f};
        c = __builtin_amdgcn_mfma_f32_16x16x32_bf16(mt ? a10 : a00, qf[nt][0], c, 0, 0, 0);
        c = __builtin_amdgcn_mfma_f32_16x16x32_bf16(mt ? a11 : a01, qf[nt][1], c, 0, 0, 0);
        sacc[mt][nt] = c;
      }
    __builtin_amdgcn_s_setprio(0);

    // no-max: p = 2^t; wave-local ps round-trip (no barrier needed)
#pragma unroll
    for (int nt = 0; nt < 5; ++nt) {
      float zl = 0.f;
#pragma unroll
      for (int mt = 0; mt < 2; ++mt) {
        bf16x4 pw;
#pragma unroll
        for (int r = 0; r < 4; ++r) {
          const float p = exp2f(sacc[mt][nt][r]);
          zl += p;
          pw[r] = (short)bf16_rne(p);
        }
        *(bf16x4*)&sm.ps[w][(nt * 16 + l15) * 40 + mt * 16 + quad * 4] = pw;
      }
      zrun[nt] += zl;
    }

    // V fragments from LDS
    bf16x8 vbf[4];
#pragma unroll
    for (int dt = 0; dt < 4; ++dt) {
      const int d = dt * 16 + l15;
      vbf[dt] = *(const bf16x8*)&vcur[(d << 7) + (((w * 4 + quad) ^ l15) << 3)];
    }

    // PV: O[qr][d] += P[qr][s]·V[s][d]
    __builtin_amdgcn_s_setprio(1);
#pragma unroll
    for (int mtq = 0; mtq < 5; ++mtq) {
      const bf16x8 pa = *(const bf16x8*)&sm.ps[w][(mtq * 16 + l15) * 40 + quad * 8];
#pragma unroll
      for (int dt = 0; dt < 4; ++dt)
        oacc[mtq][dt] = __builtin_amdgcn_mfma_f32_16x16x32_bf16(pa, vbf[dt], oacc[mtq][dt], 0, 0, 0);
    }
    __builtin_amdgcn_s_setprio(0);
    __syncthreads();  // readers of buf[st&1] done + drains prefetch of st+1
  }

  // Z: reduce over quads in-wave, stash per-wave rows (zred unions dead vt)
#pragma unroll
  for (int nt = 0; nt < 5; ++nt) {
    float z = zrun[nt];
    z += __shfl_xor(z, 16);
    z += __shfl_xor(z, 32);
    if (quad == 0) sm.b.zred[w][nt * 16 + l15] = z;
  }
  for (int i = tid; i < QROWS * 64; i += 256) sm.a.obuf[i] = 0.f;
  __syncthreads();
#pragma unroll
  for (int mtq = 0; mtq < 5; ++mtq)
#pragma unroll
    for (int r = 0; r < 4; ++r) {
      const int qr = mtq * 16 + quad * 4 + r;
#pragma unroll
      for (int dt = 0; dt < 4; ++dt)
        atomicAdd(&sm.a.obuf[qr * 64 + dt * 16 + l15], oacc[mtq][dt][r]);
    }
  __syncthreads();
  {  // normalized direct store: 80 rows x 4 segs = 320 work items
#pragma unroll
    for (int it = 0; it < 2; ++it) {
      const int tt = it * 256 + tid;
      if (tt < QROWS * 4) {
        const int qr = tt >> 2, seg = tt & 3;
        const int l = l0 + qr;
        if (l < U_SEL) {
          const float Zt = sm.b.zred[0][qr] + sm.b.zred[1][qr] +
                           sm.b.zred[2][qr] + sm.b.zred[3][qr];
          const float inv = 1.0f / Zt;
          const int row = tkb[l];
          float* op = &out[((size_t)bh * T_DIM + row) * 64 + seg * 16];
          const float* ob = &sm.a.obuf[qr * 64 + seg * 16];
#pragma unroll
          for (int j = 0; j < 4; ++j) {
            float4 o;
            o.x = ob[j * 4 + 0] * inv;
            o.y = ob[j * 4 + 1] * inv;
            o.z = ob[j * 4 + 2] * inv;
            o.w = ob[j * 4 + 3] * inv;
            *(float4*)&op[j * 4] = o;
          }
        }
      }
    }
  }
}

extern "C" void kernel_launch(void* const* d_in, const int* in_sizes, int n_in,
                              void* d_out, int out_size, void* d_ws, size_t ws_size,
                              hipStream_t stream) {
  const float* q = (const float*)d_in[0];
  const float* k = (const float*)d_in[1];
  const float* v = (const float*)d_in[2];
  float* out = (float*)d_out;
  // workspace: zw 1MB | topk 80KB | kimg 16MB | vt 8MB | qimg 16MB (~41.3MB)
  char* ws = (char*)d_ws;
  float2* zw = (float2*)ws;                                  // [2][32][2048] float2
  int* topk = (int*)(ws + 1048576);
  unsigned short* kimg = (unsigned short*)(ws + 1310720);    // 32 bh x 32 tiles x 16 KB
  unsigned short* vt_g = (unsigned short*)(ws + 18087936);   // 32 bh x 16 tiles x 16 KB
  unsigned short* qimg = (unsigned short*)(ws + 26476544);   // 32 bh x 32 tiles x 16 KB

  convert_kernel<<<dim3(3072), dim3(256), 0, stream>>>(k, v, q, kimg, vt_g, qimg, out);
  kl_score_mfma<<<dim3(1024), dim3(256), 0, stream>>>(qimg, kimg, zw);
  topk_kernel<<<dim3(BH_DIM), dim3(1024), 0, stream>>>(zw, topk);
  sparse_attn_mfma<<<dim3(256), dim3(256), 0, stream>>>(q, kimg, vt_g, topk, out);
}

// Round 9
// 230.579 us; speedup vs baseline: 2.8329x; 1.0088x over previous
//
#include <hip/hip_runtime.h>
#include <math.h>

#define T_DIM 2048
#define S_DIM 2048
#define D_DIM 64
#define BH_DIM 32
#define U_SEL 614
#define QROWS 80
#define LOG_S_D 7.624618986159398
#define LOG2E_F 1.4426950408889634f
#define LN2_D 0.6931471805599453
#define SCL_Q (0.125f * LOG2E_F)  // q scale folded with log2e: scores in log2 domain

typedef __attribute__((ext_vector_type(8))) short bf16x8;
typedef __attribute__((ext_vector_type(4))) short bf16x4;
typedef __attribute__((ext_vector_type(4))) float f32x4;

__device__ __forceinline__ unsigned short bf16_rne(float x) {
  unsigned u = __float_as_uint(x);
  u += 0x7FFF + ((u >> 16) & 1);
  return (unsigned short)(u >> 16);
}
__device__ __forceinline__ float bf16_to_f(unsigned short h) {
  return __uint_as_float(((unsigned)h) << 16);
}
// ROUND-8 LESSON: raw inline-asm v_exp_f32 is WRONG — TRANS ops need a
// compiler-inserted wait state before a dependent VALU consumer; inline asm
// hides the hazard (absmax 0.25 failure). Use exp2f / the builtin only.

#define GLD_LDS16(g, l)                                                        \
  __builtin_amdgcn_global_load_lds(                                            \
      (const __attribute__((address_space(1))) unsigned int*)(const void*)(g), \
      (__attribute__((address_space(3))) unsigned int*)(void*)(l), 16, 0, 0)

// stage 16 KB image: 4 waves x 4 instr x 64 lanes x 16 B
__device__ __forceinline__ void stage_img16(const unsigned short* __restrict__ g,
                                            unsigned short* l, int lane, int w) {
#pragma unroll
  for (int it = 0; it < 4; ++it) {
    const int chunk = it * 4 + w;
    GLD_LDS16((const char*)g + chunk * 1024 + lane * 16, (char*)l + chunk * 1024);
  }
}
// stage 8 KB image: 4 waves x 2 instr
__device__ __forceinline__ void stage_img8(const unsigned short* __restrict__ g,
                                           unsigned short* l, int lane, int w) {
#pragma unroll
  for (int it = 0; it < 2; ++it) {
    const int chunk = it * 4 + w;
    GLD_LDS16((const char*)g + chunk * 1024 + lane * 16, (char*)l + chunk * 1024);
  }
}

// swizzled image, 64-wide rows: element (r,d) at r*64 + ((d>>3)^(r&7))*8 + (d&7)
__device__ __forceinline__ bf16x8 ldfrag_sw(const unsigned short* buf, int row, int chunk) {
  return *(const bf16x8*)(buf + (row << 6) + (((chunk) ^ (row & 7)) << 3));
}
// two stacked 64-row images (rows 0..127)
__device__ __forceinline__ bf16x8 ldfrag_k128(const unsigned short* buf, int row, int chunk) {
  return *(const bf16x8*)(buf + ((row >> 6) << 12) + ((row & 63) << 6) +
                          (((chunk) ^ (row & 7)) << 3));
}

// ====== convert: K,Q -> 64-row tiles [hi 8KB | lo 8KB] swizzled; V -> V^T; zero(out) ======
// Q images carry the 0.125*log2e scale folded in (Phase A stages them directly).
__global__ __launch_bounds__(256) void convert_kernel(
    const float* __restrict__ kin, const float* __restrict__ vin,
    const float* __restrict__ qin, unsigned short* __restrict__ kimg,
    unsigned short* __restrict__ vt_g, unsigned short* __restrict__ qimg,
    float* __restrict__ out) {
  __shared__ float vld[128][65];
  const int jb = blockIdx.x;
  const int tid = threadIdx.x;
  if (jb < 2048) {  // K (jb<1024) or Q (1024..2047): 32 bh x 32 tiles of 64 rows
    const bool isq = jb >= 1024;
    const int jj = jb & 1023;
    const int bh = jj >> 5, tl = jj & 31;
    const float* src = (isq ? qin : kin) + ((size_t)bh * 2048 + tl * 64) * 64;
    unsigned short* dst = (isq ? qimg : kimg) + (size_t)(bh * 32 + tl) * 8192;
    const float scl = isq ? SCL_Q : 1.0f;
#pragma unroll
    for (int g = 0; g < 2; ++g) {
      const int flat = g * 256 + tid;  // 512 chunks = 64 rows x 8
      const int r = flat >> 3, c = flat & 7;
      const float4 f0 = *(const float4*)(src + r * 64 + c * 8);
      const float4 f1 = *(const float4*)(src + r * 64 + c * 8 + 4);
      const float xs[8] = {f0.x, f0.y, f0.z, f0.w, f1.x, f1.y, f1.z, f1.w};
      bf16x8 hv, lv;
#pragma unroll
      for (int j = 0; j < 8; ++j) {
        const float x = xs[j] * scl;
        const unsigned short h = bf16_rne(x);
        hv[j] = (short)h;
        lv[j] = (short)bf16_rne(x - bf16_to_f(h));
      }
      const int base = (r << 6) + ((c ^ (r & 7)) << 3);
      *(bf16x8*)(dst + base) = hv;
      *(bf16x8*)(dst + 4096 + base) = lv;
    }
  } else if (jb < 2560) {  // V^T: [64 d][128 s] bf16, chunk ^ (d&15)
    const int jv = jb - 2048;
    const int bh = jv >> 4, tl = jv & 15;
    const float* src = vin + ((size_t)bh * 2048 + tl * 128) * 64;
#pragma unroll
    for (int g = 0; g < 8; ++g) {
      const int f = g * 256 + tid;
      const int r = f >> 4, c4 = f & 15;
      const float4 x = *(const float4*)(src + r * 64 + c4 * 4);
      vld[r][c4 * 4 + 0] = x.x;
      vld[r][c4 * 4 + 1] = x.y;
      vld[r][c4 * 4 + 2] = x.z;
      vld[r][c4 * 4 + 3] = x.w;
    }
    __syncthreads();
    unsigned short* dst = vt_g + (size_t)(bh * 16 + tl) * 8192;
#pragma unroll
    for (int g = 0; g < 4; ++g) {
      const int oc = g * 256 + tid;
      const int d = oc >> 4, cc = oc & 15;
      bf16x8 hv;
#pragma unroll
      for (int j = 0; j < 8; ++j) hv[j] = (short)bf16_rne(vld[cc * 8 + j][d]);
      *(bf16x8*)(dst + (d << 7) + (((cc ^ (d & 15))) << 3)) = hv;
    }
  } else {  // zero d_out: 512 blocks x 2048 float4
    float4* o4 = (float4*)out;
    const size_t b = (size_t)(jb - 2560);
#pragma unroll
    for (int g = 0; g < 8; ++g)
      o4[b * 2048 + g * 256 + tid] = make_float4(0.f, 0.f, 0.f, 0.f);
  }
}

// ====== Phase A: partial (Z,W) per (t-row, s-half), bf16x3 MFMA, BK=64 dbuf ======
// grid 1024: bh = b&31 (XCD-local), ttile = (b>>5)&15, shalf = b>>9.
// ROUND-6 LESSON: co-resident same-bh blocks MUST walk the same K stream in
// lockstep (shalf 2-way only); 4-way s-sharding destroyed L2 temporal sharing.
// ROUND-9: (256,2) bound — the old (256,4) capped arch VGPRs at 64 while ~85+
// values are live, forcing AGPR shuttle copies (VALU) every iteration.
__global__ __launch_bounds__(256, 2) void kl_score_mfma(
    const unsigned short* __restrict__ qimg, const unsigned short* __restrict__ kimg,
    float2* __restrict__ zw) {
  __shared__ __align__(16) unsigned short lbuf[2][8192];  // 2 x 16 KB
  const int b = blockIdx.x;
  const int bh = b & 31;
  const int tt = (b >> 5) & 15;
  const int shalf = b >> 9;
  const int tid = threadIdx.x;
  const int lane = tid & 63, w = tid >> 6, quad = lane >> 4, l15 = lane & 15;
  const unsigned short* qb = qimg + (size_t)(bh * 32 + tt * 2) * 8192;
  const unsigned short* kb = kimg + (size_t)bh * (32 * 8192);
  const int tg0 = shalf * 16;

  // stage the 2 q tiles (rows 0-63 -> lbuf[0], rows 64-127 -> lbuf[1])
  stage_img16(qb, &lbuf[0][0], lane, w);
  stage_img16(qb + 8192, &lbuf[1][0], lane, w);
  __syncthreads();

  bf16x8 ah[2][2], al[2][2];  // persistent q A-fragments (wave w: t-rows w*32..w*32+31)
#pragma unroll
  for (int rt = 0; rt < 2; ++rt) {
    const int row = w * 32 + rt * 16 + l15;
    const unsigned short* lb = &lbuf[row >> 6][0];  // [hi 4096 | lo 4096] per tile
    const int r64 = row & 63;
#pragma unroll
    for (int kc = 0; kc < 2; ++kc) {
      const int off = (r64 << 6) + (((kc * 4 + quad) ^ (r64 & 7)) << 3);
      ah[rt][kc] = *(const bf16x8*)(lb + off);
      al[rt][kc] = *(const bf16x8*)(lb + 4096 + off);
    }
  }
  __syncthreads();  // all q frags in registers; lbuf free

  stage_img16(kb + (size_t)tg0 * 8192, &lbuf[0][0], lane, w);
  __syncthreads();  // drain tile 0

  float Zf[8], Wf[8];
#pragma unroll
  for (int i = 0; i < 8; ++i) { Zf[i] = 0.f; Wf[i] = 0.f; }

  for (int t = 0; t < 16; ++t) {
    if (t < 15)
      stage_img16(kb + (size_t)(tg0 + t + 1) * 8192, &lbuf[(t + 1) & 1][0], lane, w);
    const unsigned short* cb = &lbuf[t & 1][0];  // [hi 4096 | lo 4096] elems, 64 rows

    f32x4 acc[2][4];
#pragma unroll
    for (int rt = 0; rt < 2; ++rt)
#pragma unroll
      for (int ct = 0; ct < 4; ++ct) acc[rt][ct] = (f32x4){0.f, 0.f, 0.f, 0.f};

#pragma unroll
    for (int ct = 0; ct < 4; ++ct) {
      const int srow = ct * 16 + l15;
      const bf16x8 bh0 = ldfrag_sw(cb, srow, quad);
      const bf16x8 bl0 = ldfrag_sw(cb + 4096, srow, quad);
      const bf16x8 bh1 = ldfrag_sw(cb, srow, 4 + quad);
      const bf16x8 bl1 = ldfrag_sw(cb + 4096, srow, 4 + quad);
#pragma unroll
      for (int rt = 0; rt < 2; ++rt) {
        f32x4 c = acc[rt][ct];
        c = __builtin_amdgcn_mfma_f32_16x16x32_bf16(ah[rt][0], bh0, c, 0, 0, 0);
        c = __builtin_amdgcn_mfma_f32_16x16x32_bf16(al[rt][0], bh0, c, 0, 0, 0);
        c = __builtin_amdgcn_mfma_f32_16x16x32_bf16(ah[rt][0], bl0, c, 0, 0, 0);
        c = __builtin_amdgcn_mfma_f32_16x16x32_bf16(ah[rt][1], bh1, c, 0, 0, 0);
        c = __builtin_amdgcn_mfma_f32_16x16x32_bf16(al[rt][1], bh1, c, 0, 0, 0);
        c = __builtin_amdgcn_mfma_f32_16x16x32_bf16(ah[rt][1], bl1, c, 0, 0, 0);
        acc[rt][ct] = c;
      }
    }

    // no-max epilogue (log2 domain): e = 2^t, W += e*t  (fp32 accumulators)
#pragma unroll
    for (int rt = 0; rt < 2; ++rt)
#pragma unroll
      for (int r = 0; r < 4; ++r) {
        float zp = 0.f, wp = 0.f;
#pragma unroll
        for (int ct = 0; ct < 4; ++ct) {
          const float tv = acc[rt][ct][r];
          const float e = exp2f(tv);
          zp += e;
          wp = fmaf(e, tv, wp);
        }
        Zf[rt * 4 + r] += zp;
        Wf[rt * 4 + r] += wp;
      }
    __syncthreads();  // readers done; drains prefetch of t+1
  }

#pragma unroll
  for (int i = 0; i < 8; ++i) {
    float Zt = Zf[i], Wt = Wf[i];
#pragma unroll
    for (int mask = 1; mask <= 8; mask <<= 1) {
      Zt += __shfl_xor(Zt, mask);
      Wt += __shfl_xor(Wt, mask);
    }
    if (l15 == 0) {
      const int row = tt * 128 + w * 32 + (i >> 2) * 16 + quad * 4 + (i & 3);
      zw[((size_t)shalf * 32 + bh) * 2048 + row] = make_float2(Zt, Wt);
    }
  }
}

// ====== Phase B: kl from (Z,W) halves + exact top-614, bitonic, 1024 threads ======
__global__ __launch_bounds__(1024) void topk_kernel(const float2* __restrict__ zw,
                                                    int* __restrict__ topk) {
  __shared__ float sv[2048];
  __shared__ int si[2048];
  const int bh = blockIdx.x;
  const int tid = threadIdx.x;
  for (int i = tid; i < 2048; i += 1024) {
    const float2 a = zw[(size_t)bh * 2048 + i];
    const float2 c = zw[(size_t)(32 + bh) * 2048 + i];
    const double Z = (double)a.x + (double)c.x;
    const double W = (double)a.y + (double)c.y;
    sv[i] = (float)(LN2_D * (W / Z) - log(Z) + LOG_S_D);
    si[i] = i;
  }
  __syncthreads();
  for (int kk = 2; kk <= 2048; kk <<= 1) {
    for (int j = kk >> 1; j > 0; j >>= 1) {
      const int p = tid;
      const int i = ((p & ~(j - 1)) << 1) | (p & (j - 1));
      const int pr = i | j;
      const float v1 = sv[i], v2 = sv[pr];
      const int i1 = si[i], i2 = si[pr];
      const bool beforePI = (v2 > v1) || (v2 == v1 && i2 < i1);
      const bool dirDesc = ((i & kk) == 0);
      const bool doSwap = dirDesc ? beforePI : !beforePI;
      if (doSwap) { sv[i] = v2; sv[pr] = v1; si[i] = i2; si[pr] = i1; }
      __syncthreads();
    }
  }
  for (int i = tid; i < U_SEL; i += 1024) topk[bh * U_SEL + i] = si[i];
}

// ====== Phase C: bf16 MFMA attention, 256 blocks = EXACTLY 1 block/CU ======
// Round-4/5 lesson: wall time = per-block serial time x worst-CU block count.
// Perfectly balanced grid (8 l-tiles x 80 rows x 32 bh = 256 blocks), full
// 2048-s loop per block, ps-LDS P path, K+V double-buffered, one barrier/iter.
struct __align__(16) SmC {
  union { unsigned short kt[2][8192]; float obuf[QROWS * 64]; } a;  // 32 KB (obuf after loop)
  union { unsigned short vt[2][8192]; float zred[4][QROWS]; } b;    // 32 KB (zred after loop)
  unsigned short qs[QROWS * 64];                                    // 10 KB
  unsigned short ps[4][QROWS * 40];                                 // 25.6 KB
};

// grid 256: bh = b&31 (XCD-affine), lt = b>>5
__global__ __launch_bounds__(256, 1) void sparse_attn_mfma(
    const float* __restrict__ q, const unsigned short* __restrict__ kimg,
    const unsigned short* __restrict__ vt_g, const int* __restrict__ topk,
    float* __restrict__ out) {
  __shared__ SmC sm;
  const int b = blockIdx.x;
  const int bh = b & 31;
  const int l0 = (b >> 5) * QROWS;
  const int tid = threadIdx.x;
  const int lane = tid & 63, w = tid >> 6, quad = lane >> 4, l15 = lane & 15;
  const float* qb = q + (size_t)bh * (2048 * 64);
  const unsigned short* kb = kimg + (size_t)bh * (32 * 8192);
  const unsigned short* vtb = vt_g + (size_t)bh * (16 * 8192);
  const int* tkb = topk + bh * U_SEL;

  {  // gather 80 selected q rows -> bf16 * (0.125*log2e), swizzled image in LDS
#pragma unroll
    for (int g = 0; g < 3; ++g) {
      const int ch = g * 256 + tid;
      if (ch < QROWS * 8) {
        const int r = ch >> 3, c = ch & 7;
        const int l = l0 + r;
        const int row = (l < U_SEL) ? tkb[l] : tkb[0];
        const float4 f0 = *(const float4*)(qb + (size_t)row * 64 + c * 8);
        const float4 f1 = *(const float4*)(qb + (size_t)row * 64 + c * 8 + 4);
        const float xs[8] = {f0.x, f0.y, f0.z, f0.w, f1.x, f1.y, f1.z, f1.w};
        bf16x8 hv;
#pragma unroll
        for (int j = 0; j < 8; ++j) hv[j] = (short)bf16_rne(xs[j] * SCL_Q);
        *(bf16x8*)&sm.qs[(r << 6) + ((c ^ (r & 7)) << 3)] = hv;
      }
    }
  }
  // prologue: stage tile 0 (K-hi 16 KB + V^T 16 KB) into buffer 0
  stage_img8(kb, sm.a.kt[0], lane, w);
  stage_img8(kb + 8192, sm.a.kt[0] + 4096, lane, w);
  stage_img16(vtb, sm.b.vt[0], lane, w);
  __syncthreads();  // qs ready + tile 0 drained

  bf16x8 qf[5][2];  // persistent q B-fragments (80 rows -> 5 nt tiles)
#pragma unroll
  for (int nt = 0; nt < 5; ++nt)
#pragma unroll
    for (int kc = 0; kc < 2; ++kc)
      qf[nt][kc] = ldfrag_sw(sm.qs, nt * 16 + l15, kc * 4 + quad);

  float zrun[5] = {0.f, 0.f, 0.f, 0.f, 0.f};
  f32x4 oacc[5][4];
#pragma unroll
  for (int a = 0; a < 5; ++a)
#pragma unroll
    for (int b2 = 0; b2 < 4; ++b2) oacc[a][b2] = (f32x4){0.f, 0.f, 0.f, 0.f};

  for (int st = 0; st < 16; ++st) {
    // prefetch tile st+1 into the other buffer; drained by the single barrier.
    if (st < 15) {
      unsigned short* kd = sm.a.kt[(st + 1) & 1];
      unsigned short* vd = sm.b.vt[(st + 1) & 1];
      stage_img8(kb + (size_t)(2 * st + 2) * 8192, kd, lane, w);
      stage_img8(kb + (size_t)(2 * st + 3) * 8192, kd + 4096, lane, w);
      stage_img16(vtb + (size_t)(st + 1) * 8192, vd, lane, w);
    }
    const unsigned short* kcur = sm.a.kt[st & 1];
    const unsigned short* vcur = sm.b.vt[st & 1];

    // S^T = K·q^T : C[m=s][n=qr]; wave w owns s in [w*32, w*32+32)
    const int ar0 = w * 32 + l15, ar1 = w * 32 + 16 + l15;
    const bf16x8 a00 = ldfrag_k128(kcur, ar0, quad);
    const bf16x8 a01 = ldfrag_k128(kcur, ar0, 4 + quad);
    const bf16x8 a10 = ldfrag_k128(kcur, ar1, quad);
    const bf16x8 a11 = ldfrag_k128(kcur, ar1, 4 + quad);

    f32x4 sacc[2][5];
    __builtin_amdgcn_s_setprio(1);
#pragma unroll
    for (int mt = 0; mt < 2; ++mt)
#pragma unroll
      for (int nt = 0; nt < 5; ++nt) {
        f32x4 c = (f32x4){0.f, 0.f, 0.f, 0.f};
        c = __builtin_amdgcn_mfma_f32_16x16x32_bf16(mt ? a10 : a00, qf[nt][0], c, 0, 0, 0);
        c = __builtin_amdgcn_mfma_f32_16x16x32_bf16(mt ? a11 : a01, qf[nt][1], c, 0, 0, 0);
        sacc[mt][nt] = c;
      }
    __builtin_amdgcn_s_setprio(0);

    // no-max: p = 2^t; wave-local ps round-trip (no barrier needed)
#pragma unroll
    for (int nt = 0; nt < 5; ++nt) {
      float zl = 0.f;
#pragma unroll
      for (int mt = 0; mt < 2; ++mt) {
        bf16x4 pw;
#pragma unroll
        for (int r = 0; r < 4; ++r) {
          const float p = exp2f(sacc[mt][nt][r]);
          zl += p;
          pw[r] = (short)bf16_rne(p);
        }
        *(bf16x4*)&sm.ps[w][(nt * 16 + l15) * 40 + mt * 16 + quad * 4] = pw;
      }
      zrun[nt] += zl;
    }

    // V fragments from LDS
    bf16x8 vbf[4];
#pragma unroll
    for (int dt = 0; dt < 4; ++dt) {
      const int d = dt * 16 + l15;
      vbf[dt] = *(const bf16x8*)&vcur[(d << 7) + (((w * 4 + quad) ^ l15) << 3)];
    }

    // PV: O[qr][d] += P[qr][s]·V[s][d]
    __builtin_amdgcn_s_setprio(1);
#pragma unroll
    for (int mtq = 0; mtq < 5; ++mtq) {
      const bf16x8 pa = *(const bf16x8*)&sm.ps[w][(mtq * 16 + l15) * 40 + quad * 8];
#pragma unroll
      for (int dt = 0; dt < 4; ++dt)
        oacc[mtq][dt] = __builtin_amdgcn_mfma_f32_16x16x32_bf16(pa, vbf[dt], oacc[mtq][dt], 0, 0, 0);
    }
    __builtin_amdgcn_s_setprio(0);
    __syncthreads();  // readers of buf[st&1] done + drains prefetch of st+1
  }

  // Z: reduce over quads in-wave, stash per-wave rows (zred unions dead vt)
#pragma unroll
  for (int nt = 0; nt < 5; ++nt) {
    float z = zrun[nt];
    z += __shfl_xor(z, 16);
    z += __shfl_xor(z, 32);
    if (quad == 0) sm.b.zred[w][nt * 16 + l15] = z;
  }
  for (int i = tid; i < QROWS * 64; i += 256) sm.a.obuf[i] = 0.f;
  __syncthreads();
#pragma unroll
  for (int mtq = 0; mtq < 5; ++mtq)
#pragma unroll
    for (int r = 0; r < 4; ++r) {
      const int qr = mtq * 16 + quad * 4 + r;
#pragma unroll
      for (int dt = 0; dt < 4; ++dt)
        atomicAdd(&sm.a.obuf[qr * 64 + dt * 16 + l15], oacc[mtq][dt][r]);
    }
  __syncthreads();
  {  // normalized direct store: 80 rows x 4 segs = 320 work items
#pragma unroll
    for (int it = 0; it < 2; ++it) {
      const int tt = it * 256 + tid;
      if (tt < QROWS * 4) {
        const int qr = tt >> 2, seg = tt & 3;
        const int l = l0 + qr;
        if (l < U_SEL) {
          const float Zt = sm.b.zred[0][qr] + sm.b.zred[1][qr] +
                           sm.b.zred[2][qr] + sm.b.zred[3][qr];
          const float inv = 1.0f / Zt;
          const int row = tkb[l];
          float* op = &out[((size_t)bh * T_DIM + row) * 64 + seg * 16];
          const float* ob = &sm.a.obuf[qr * 64 + seg * 16];
#pragma unroll
          for (int j = 0; j < 4; ++j) {
            float4 o;
            o.x = ob[j * 4 + 0] * inv;
            o.y = ob[j * 4 + 1] * inv;
            o.z = ob[j * 4 + 2] * inv;
            o.w = ob[j * 4 + 3] * inv;
            *(float4*)&op[j * 4] = o;
          }
        }
      }
    }
  }
}

extern "C" void kernel_launch(void* const* d_in, const int* in_sizes, int n_in,
                              void* d_out, int out_size, void* d_ws, size_t ws_size,
                              hipStream_t stream) {
  const float* q = (const float*)d_in[0];
  const float* k = (const float*)d_in[1];
  const float* v = (const float*)d_in[2];
  float* out = (float*)d_out;
  // workspace: zw 1MB | topk 80KB | kimg 16MB | vt 8MB | qimg 16MB (~41.3MB)
  char* ws = (char*)d_ws;
  float2* zw = (float2*)ws;                                  // [2][32][2048] float2
  int* topk = (int*)(ws + 1048576);
  unsigned short* kimg = (unsigned short*)(ws + 1310720);    // 32 bh x 32 tiles x 16 KB
  unsigned short* vt_g = (unsigned short*)(ws + 18087936);   // 32 bh x 16 tiles x 16 KB
  unsigned short* qimg = (unsigned short*)(ws + 26476544);   // 32 bh x 32 tiles x 16 KB

  convert_kernel<<<dim3(3072), dim3(256), 0, stream>>>(k, v, q, kimg, vt_g, qimg, out);
  kl_score_mfma<<<dim3(1024), dim3(256), 0, stream>>>(qimg, kimg, zw);
  topk_kernel<<<dim3(BH_DIM), dim3(1024), 0, stream>>>(zw, topk);
  sparse_attn_mfma<<<dim3(256), dim3(256), 0, stream>>>(q, kimg, vt_g, topk, out);
}